// Round 2
// baseline (2340.039 us; speedup 1.0000x reference)
//
#include <hip/hip_runtime.h>

#define N_EMBD 512
#define HID 66
#define T_STEPS 8
#define BLK 128

__device__ __forceinline__ float fast_rcp(float a) {
    float r = __builtin_amdgcn_rcpf(a);
    r = r * (2.0f - a * r);   // one Newton step -> ~1e-7 rel
    return r;
}
__device__ __forceinline__ float fast_exp(float x) {
    // clamp to avoid inf -> NaN in Newton rcp
    x = fminf(x, 60.0f);
    return __expf(x);
}
__device__ __forceinline__ float sigmoid_f(float x) {
    return fast_rcp(1.0f + fast_exp(-x));
}
__device__ __forceinline__ float tanh_f(float x) {
    // 1 - 2/(e^{2x}+1): exact at saturation, no inf/NaN
    return 1.0f - 2.0f * fast_rcp(1.0f + fast_exp(2.0f * x));
}

__global__ __launch_bounds__(BLK, 2) void wp_grurefine_kernel(
    const float* __restrict__ x_last,      // [B,8,2]
    const float* __restrict__ cls_emb,     // [B,512]
    const float* __restrict__ tp,          // [B,2]
    const float* __restrict__ light,       // [B,1]
    const float* __restrict__ cmd,         // [B,1]
    const float* __restrict__ bbox,        // [B,1,8,10]
    const float* __restrict__ W_head,      // [64,512]
    const float* __restrict__ b_head,      // [64]
    const float* __restrict__ W_ih,        // [198,16]
    const float* __restrict__ W_hh,        // [198,66]
    const float* __restrict__ b_ih,        // [198]
    const float* __restrict__ b_hh,        // [198]
    const float* __restrict__ W_out,       // [2,66]
    const float* __restrict__ b_out,       // [2]
    float* __restrict__ out,               // [B,8,2]
    int Btotal)
{
    __shared__ float h_lds[BLK][HID];      // per-thread private row; no barriers
    const int tl = threadIdx.x;
    const int b  = blockIdx.x * BLK + tl;
    if (b >= Btotal) return;

    // ---------------- head: z0[0:64] = cls_emb[b] @ W_head.T + b_head ----------------
    float h[HID];
    #pragma unroll
    for (int j = 0; j < 64; ++j) h[j] = b_head[j];

    const float* cls = cls_emb + (size_t)b * N_EMBD;
    #pragma unroll 1
    for (int k0 = 0; k0 < N_EMBD; k0 += 4) {
        const float4 c = *(const float4*)(cls + k0);
        #pragma unroll
        for (int j = 0; j < 64; ++j) {
            const float* wr = W_head + j * N_EMBD + k0;   // wave-uniform -> s_load
            h[j] = fmaf(c.x, wr[0],
                   fmaf(c.y, wr[1],
                   fmaf(c.z, wr[2],
                   fmaf(c.w, wr[3], h[j]))));
        }
    }
    h[64] = light[b];
    h[65] = cmd[b];

    // seed LDS copy of h (for runtime-j access inside the gate loop)
    #pragma unroll
    for (int j = 0; j < HID; ++j) h_lds[tl][j] = h[j];

    // ---------------- GRU over 8 steps ----------------
    const float tp0 = tp[(size_t)b * 2 + 0];
    const float tp1 = tp[(size_t)b * 2 + 1];
    const float* xlr = x_last + (size_t)b * (T_STEPS * 2);
    const float* bbr = bbox   + (size_t)b * (T_STEPS * 10);
    float*       outr = out   + (size_t)b * (T_STEPS * 2);

    float x0 = 0.0f, x1 = 0.0f;

    #pragma unroll 1
    for (int t = 0; t < T_STEPS; ++t) {
        float xin[16];
        xin[0] = x0;  xin[1] = x1;
        xin[2] = tp0; xin[3] = tp1;
        xin[4] = xlr[t * 2 + 0];
        xin[5] = xlr[t * 2 + 1];
        #pragma unroll
        for (int q = 0; q < 10; ++q) xin[6 + q] = bbr[t * 10 + q];

        // gate loop: rolled j (uniform weight rows -> scalar loads),
        // unrolled k (h[k]/xin[k] constant-indexed -> registers)
        #pragma unroll 1
        for (int j = 0; j < HID; ++j) {
            const float* wir = W_ih + j * 16;
            const float* wiu = W_ih + (HID + j) * 16;
            const float* win = W_ih + (2 * HID + j) * 16;
            const float* whr = W_hh + j * HID;
            const float* whu = W_hh + (HID + j) * HID;
            const float* whn = W_hh + (2 * HID + j) * HID;

            float gr  = b_ih[j]           + b_hh[j];
            float gu  = b_ih[HID + j]     + b_hh[HID + j];
            float gin = b_ih[2 * HID + j];
            float ghn = b_hh[2 * HID + j];

            #pragma unroll
            for (int k = 0; k < 16; ++k) {
                gr  = fmaf(xin[k], wir[k], gr);
                gu  = fmaf(xin[k], wiu[k], gu);
                gin = fmaf(xin[k], win[k], gin);
            }
            #pragma unroll
            for (int k = 0; k < HID; ++k) {
                gr  = fmaf(h[k], whr[k], gr);
                gu  = fmaf(h[k], whu[k], gu);
                ghn = fmaf(h[k], whn[k], ghn);
            }

            const float r = sigmoid_f(gr);
            const float u = sigmoid_f(gu);
            const float n = tanh_f(fmaf(r, ghn, gin));
            const float hold = h_lds[tl][j];          // old h[j], runtime j
            h_lds[tl][j] = (1.0f - u) * n + u * hold; // z_new[j]
        }

        // copy back z_new -> h regs, fused with output head
        float a0 = b_out[0], a1 = b_out[1];
        #pragma unroll
        for (int j = 0; j < HID; ++j) {
            const float z = h_lds[tl][j];
            h[j] = z;
            a0 = fmaf(z, W_out[j],       a0);
            a1 = fmaf(z, W_out[HID + j], a1);
        }
        x0 += a0;
        x1 += a1;

        outr[t * 2 + 0] = x0 - 1.3f;
        outr[t * 2 + 1] = x1;
    }
}

extern "C" void kernel_launch(void* const* d_in, const int* in_sizes, int n_in,
                              void* d_out, int out_size, void* d_ws, size_t ws_size,
                              hipStream_t stream) {
    const float* x_last  = (const float*)d_in[0];
    const float* cls_emb = (const float*)d_in[1];
    const float* tp      = (const float*)d_in[2];
    const float* light   = (const float*)d_in[3];
    const float* cmd     = (const float*)d_in[4];
    const float* bbox    = (const float*)d_in[5];
    const float* W_head  = (const float*)d_in[6];
    const float* b_head  = (const float*)d_in[7];
    const float* W_ih    = (const float*)d_in[8];
    const float* W_hh    = (const float*)d_in[9];
    const float* b_ih    = (const float*)d_in[10];
    const float* b_hh    = (const float*)d_in[11];
    const float* W_out   = (const float*)d_in[12];
    const float* b_out   = (const float*)d_in[13];
    float* out = (float*)d_out;

    const int Btotal = in_sizes[1] / N_EMBD;
    dim3 grid((Btotal + BLK - 1) / BLK);
    wp_grurefine_kernel<<<grid, BLK, 0, stream>>>(
        x_last, cls_emb, tp, light, cmd, bbox,
        W_head, b_head, W_ih, W_hh, b_ih, b_hh, W_out, b_out,
        out, Btotal);
}